// Round 3
// baseline (400.302 us; speedup 1.0000x reference)
//
#include <hip/hip_runtime.h>
#include <cstdint>
#include <cstddef>

#define B_ 8
#define T_ 2048
#define F_ 512
#define D_ 256
#define NSPLIT 4   // KV split factor; keys per split-block = T_/NSPLIT = 512

typedef float f32x4 __attribute__((ext_vector_type(4)));
typedef __bf16 bf16x8 __attribute__((ext_vector_type(8)));
typedef unsigned short us8 __attribute__((ext_vector_type(8)));
typedef unsigned short us4 __attribute__((ext_vector_type(4)));

static __device__ __forceinline__ unsigned short f2bf(float f) {
  union { float f; unsigned int u; } v; v.f = f;
  unsigned int u = v.u;
  u += 0x7fffu + ((u >> 16) & 1u);   // RNE
  return (unsigned short)(u >> 16);
}

static __device__ __forceinline__ float bf2f(unsigned short s) {
  union { float f; unsigned int u; } v; v.u = ((unsigned int)s) << 16;
  return v.f;
}

static __device__ __forceinline__ bf16x8 ldb8(const unsigned short* p) {
  return *reinterpret_cast<const bf16x8*>(p);
}

static __device__ __forceinline__ f32x4 mfma_bf16(bf16x8 a, bf16x8 b, f32x4 c) {
  return __builtin_amdgcn_mfma_f32_16x16x32_bf16(a, b, c, 0, 0, 0);
}

// ---------------------------------------------------------------------------
// Kernel 1: transpose + convert the three W matrices: [F,D] f32 -> [D,F] bf16
// ---------------------------------------------------------------------------
__global__ __launch_bounds__(256) void tw_kernel(const float* __restrict__ Wq,
                                                 const float* __restrict__ Wk,
                                                 const float* __restrict__ Wv,
                                                 unsigned short* __restrict__ Wt) {
  __shared__ unsigned short tile[64][72];
  const float* W = (blockIdx.z == 0) ? Wq : (blockIdx.z == 1) ? Wk : Wv;
  unsigned short* out = Wt + (size_t)blockIdx.z * (D_ * F_);
  int k0 = blockIdx.x * 64, n0 = blockIdx.y * 64;
  int t = threadIdx.x;
#pragma unroll
  for (int i = 0; i < 4; i++) {
    int c = t + 256 * i;
    int r = c >> 4, c4 = (c & 15) * 4;
    float4 v = *reinterpret_cast<const float4*>(&W[(size_t)(k0 + r) * D_ + n0 + c4]);
    us4 p; p[0] = f2bf(v.x); p[1] = f2bf(v.y); p[2] = f2bf(v.z); p[3] = f2bf(v.w);
    *reinterpret_cast<us4*>(&tile[r][c4]) = p;
  }
  __syncthreads();
#pragma unroll
  for (int i = 0; i < 4; i++) {
    int c = t + 256 * i;
    int r = c >> 4, c4 = (c & 15) * 4;
    us4 p;
    p[0] = tile[c4 + 0][r];
    p[1] = tile[c4 + 1][r];
    p[2] = tile[c4 + 2][r];
    p[3] = tile[c4 + 3][r];
    *reinterpret_cast<us4*>(&out[(size_t)(n0 + r) * F_ + k0 + c4]) = p;
  }
}

// ---------------------------------------------------------------------------
// Kernel 2: projection GEMM.  out = X[16384,512] * W  (per z: Q/16, K, V^T)
// ---------------------------------------------------------------------------
__global__ __launch_bounds__(256) void proj_kernel(const float* __restrict__ X,
                                                   const unsigned short* __restrict__ Wt,
                                                   unsigned short* __restrict__ Qs,
                                                   unsigned short* __restrict__ Kb,
                                                   unsigned short* __restrict__ Vt) {
  __shared__ unsigned short Al[128][68];
  __shared__ unsigned short Bl[128][68];
  const int brow = blockIdx.x * 128;
  const int bcol = blockIdx.y * 128;
  const int z = blockIdx.z;
  const unsigned short* W = Wt + (size_t)z * (D_ * F_);
  const int tid = threadIdx.x;
  const int wave = tid >> 6, lane = tid & 63;
  const int wr = wave >> 1, wc = wave & 1;
  const int lg = lane >> 4, lr = lane & 15;

  f32x4 acc[4][4] = {};

  for (int k0 = 0; k0 < F_; k0 += 64) {
#pragma unroll
    for (int i = 0; i < 4; i++) {
      int c = tid + 256 * i;
      int r = c >> 3, off = (c & 7) * 8;
      float4 v0 = *reinterpret_cast<const float4*>(&X[(size_t)(brow + r) * F_ + k0 + off]);
      float4 v1 = *reinterpret_cast<const float4*>(&X[(size_t)(brow + r) * F_ + k0 + off + 4]);
      us8 p;
      p[0] = f2bf(v0.x); p[1] = f2bf(v0.y); p[2] = f2bf(v0.z); p[3] = f2bf(v0.w);
      p[4] = f2bf(v1.x); p[5] = f2bf(v1.y); p[6] = f2bf(v1.z); p[7] = f2bf(v1.w);
      *reinterpret_cast<us8*>(&Al[r][off]) = p;
      *reinterpret_cast<us8*>(&Bl[r][off]) =
          *reinterpret_cast<const us8*>(&W[(size_t)(bcol + r) * F_ + k0 + off]);
    }
    __syncthreads();
#pragma unroll
    for (int kk = 0; kk < 2; kk++) {
      bf16x8 af[4], bfr[4];
#pragma unroll
      for (int mi = 0; mi < 4; mi++) af[mi] = ldb8(&Al[wr * 64 + mi * 16 + lr][kk * 32 + lg * 8]);
#pragma unroll
      for (int ni = 0; ni < 4; ni++) bfr[ni] = ldb8(&Bl[wc * 64 + ni * 16 + lr][kk * 32 + lg * 8]);
#pragma unroll
      for (int mi = 0; mi < 4; mi++)
#pragma unroll
        for (int ni = 0; ni < 4; ni++)
          acc[mi][ni] = mfma_bf16(af[mi], bfr[ni], acc[mi][ni]);
    }
    __syncthreads();
  }

#pragma unroll
  for (int mi = 0; mi < 4; mi++) {
#pragma unroll
    for (int ni = 0; ni < 4; ni++) {
      int row0 = brow + wr * 64 + mi * 16 + lg * 4;
      int col = bcol + wc * 64 + ni * 16 + lr;
      if (z == 0) {
#pragma unroll
        for (int j = 0; j < 4; j++)
          Qs[(size_t)(row0 + j) * D_ + col] = f2bf(acc[mi][ni][j] * 0.0625f);
      } else if (z == 1) {
#pragma unroll
        for (int j = 0; j < 4; j++)
          Kb[(size_t)(row0 + j) * D_ + col] = f2bf(acc[mi][ni][j]);
      } else {
        int b = row0 >> 11, t0 = row0 & (T_ - 1);
        us4 p;
#pragma unroll
        for (int j = 0; j < 4; j++) p[j] = f2bf(acc[mi][ni][j]);
        *reinterpret_cast<us4*>(&Vt[(size_t)b * D_ * T_ + (size_t)col * T_ + t0]) = p;
      }
    }
  }
}

// ---------------------------------------------------------------------------
// Kernel 3: flash attention, barrier-free, direct-L2 K/V reads.
// grid (B, T/64, NSPLIT), block 256 (4 independent waves, 16 q-rows each).
// Block z handles keys [z*512, (z+1)*512). Partials (o bf16, m/l f32) -> ws.
// ---------------------------------------------------------------------------
__global__ __launch_bounds__(256, 3) void flash_kernel(const unsigned short* __restrict__ Qs,
                                                       const unsigned short* __restrict__ Kb,
                                                       const unsigned short* __restrict__ Vt,
                                                       unsigned short* __restrict__ op,
                                                       float2* __restrict__ ml) {
  __shared__ unsigned short Pl[4][16][68];   // per-wave P relayout, stride 34dw%32=2

  const int b = blockIdx.x, qt = blockIdx.y, h = blockIdx.z;  // XCD = linear%8 = b
  const int tid = threadIdx.x;
  const int wave = tid >> 6, lane = tid & 63;
  const int lg = lane >> 4, lr = lane & 15;

  const int qrow = qt * 64 + wave * 16 + lr;
  const unsigned short* qptr = Qs + ((size_t)b * T_ + qrow) * D_;
  bf16x8 qf[8];
#pragma unroll
  for (int ks = 0; ks < 8; ks++) qf[ks] = ldb8(qptr + ks * 32 + lg * 8);

  f32x4 o[16] = {};
  float m[4] = {-__builtin_inff(), -__builtin_inff(), -__builtin_inff(), -__builtin_inff()};
  float lsum[4] = {0.f, 0.f, 0.f, 0.f};

  const unsigned short* kbase = Kb + (size_t)b * T_ * D_;
  const unsigned short* vbase = Vt + (size_t)b * D_ * T_;

  for (int kt = 0; kt < (T_ / NSPLIT) / 64; kt++) {
    const int key0 = h * (T_ / NSPLIT) + kt * 64;

    // ---- S = Q * K^T : K B-fragments straight from L2 ----
    f32x4 s[4] = {};
#pragma unroll
    for (int ks = 0; ks < 8; ks++) {
#pragma unroll
      for (int nf = 0; nf < 4; nf++) {
        bf16x8 kb = ldb8(&kbase[(size_t)(key0 + nf * 16 + lr) * D_ + ks * 32 + lg * 8]);
        s[nf] = mfma_bf16(qf[ks], kb, s[nf]);
      }
    }

    // ---- online softmax (row q = 4*lg+j, key = 16*nf+lr) ----
    float corr[4];
#pragma unroll
    for (int j = 0; j < 4; j++) {
      float t0 = fmaxf(fmaxf(s[0][j], s[1][j]), fmaxf(s[2][j], s[3][j]));
      t0 = fmaxf(t0, __shfl_xor(t0, 1));
      t0 = fmaxf(t0, __shfl_xor(t0, 2));
      t0 = fmaxf(t0, __shfl_xor(t0, 4));
      t0 = fmaxf(t0, __shfl_xor(t0, 8));
      float mn = fmaxf(m[j], t0);
      corr[j] = __expf(m[j] - mn);
      m[j] = mn;
    }
    float rs[4] = {0.f, 0.f, 0.f, 0.f};
#pragma unroll
    for (int nf = 0; nf < 4; nf++) {
#pragma unroll
      for (int j = 0; j < 4; j++) {
        float p = __expf(s[nf][j] - m[j]);
        rs[j] += p;
        Pl[wave][lg * 4 + j][nf * 16 + lr] = f2bf(p);
      }
    }
#pragma unroll
    for (int j = 0; j < 4; j++) {
      float t0 = rs[j];
      t0 += __shfl_xor(t0, 1);
      t0 += __shfl_xor(t0, 2);
      t0 += __shfl_xor(t0, 4);
      t0 += __shfl_xor(t0, 8);
      lsum[j] = lsum[j] * corr[j] + t0;
    }
#pragma unroll
    for (int nf = 0; nf < 16; nf++) {
#pragma unroll
      for (int j = 0; j < 4; j++) o[nf][j] *= corr[j];
    }

    // ---- O += P * V : V^T B-fragments straight from L2 ----
#pragma unroll
    for (int ks = 0; ks < 2; ks++) {
      bf16x8 pa = ldb8(&Pl[wave][lr][ks * 32 + lg * 8]);
#pragma unroll
      for (int nf = 0; nf < 16; nf++) {
        bf16x8 vb = ldb8(&vbase[(size_t)(nf * 16 + lr) * T_ + key0 + ks * 32 + lg * 8]);
        o[nf] = mfma_bf16(pa, vb, o[nf]);
      }
    }
  }

  // ---- write partials (unnormalized o in bf16, m/l in f32) ----
  const size_t rowbase = (size_t)h * (B_ * T_) + (size_t)b * T_;
#pragma unroll
  for (int nf = 0; nf < 16; nf++) {
#pragma unroll
    for (int j = 0; j < 4; j++) {
      int q = qt * 64 + wave * 16 + lg * 4 + j;
      op[(rowbase + q) * D_ + nf * 16 + lr] = f2bf(o[nf][j]);
    }
  }
  if (lr == 0) {
#pragma unroll
    for (int j = 0; j < 4; j++) {
      int q = qt * 64 + wave * 16 + lg * 4 + j;
      ml[rowbase + q] = make_float2(m[j], lsum[j]);
    }
  }
}

// ---------------------------------------------------------------------------
// Kernel 4: merge NSPLIT partials.  grid (B*T/4), block 256: 4 rows/block.
// ---------------------------------------------------------------------------
__global__ __launch_bounds__(256) void merge_kernel(const unsigned short* __restrict__ op,
                                                    const float2* __restrict__ ml,
                                                    float* __restrict__ out) {
  const int tid = threadIdx.x;
  const int row = blockIdx.x * 4 + (tid >> 6);
  const int d0 = (tid & 63) * 4;

  float mh[NSPLIT], lh[NSPLIT];
  float M = -__builtin_inff();
#pragma unroll
  for (int hh = 0; hh < NSPLIT; hh++) {
    float2 v = ml[(size_t)hh * (B_ * T_) + row];
    mh[hh] = v.x; lh[hh] = v.y;
    M = fmaxf(M, v.x);
  }
  float e[NSPLIT], den = 0.f;
#pragma unroll
  for (int hh = 0; hh < NSPLIT; hh++) {
    e[hh] = __expf(mh[hh] - M);
    den += e[hh] * lh[hh];
  }
  const float inv = 1.0f / den;

  float acc[4] = {0.f, 0.f, 0.f, 0.f};
#pragma unroll
  for (int hh = 0; hh < NSPLIT; hh++) {
    us4 p = *reinterpret_cast<const us4*>(
        &op[((size_t)hh * (B_ * T_) + row) * D_ + d0]);
#pragma unroll
    for (int j = 0; j < 4; j++) acc[j] += e[hh] * bf2f(p[j]);
  }
  float4 r;
  r.x = acc[0] * inv; r.y = acc[1] * inv; r.z = acc[2] * inv; r.w = acc[3] * inv;
  *reinterpret_cast<float4*>(&out[(size_t)row * D_ + d0]) = r;
}

// ---------------------------------------------------------------------------
extern "C" void kernel_launch(void* const* d_in, const int* in_sizes, int n_in,
                              void* d_out, int out_size, void* d_ws, size_t ws_size,
                              hipStream_t stream) {
  const float* X  = (const float*)d_in[0];
  const float* Wq = (const float*)d_in[1];
  const float* Wk = (const float*)d_in[2];
  const float* Wv = (const float*)d_in[3];
  float* out = (float*)d_out;

  char* ws = (char*)d_ws;
  // Wt 0.75MB | Qs 8MB | Kb 8MB | Vt 8MB | op 32MB (bf16 partials) | ml 0.5MB
  unsigned short* Wt = (unsigned short*)ws;
  unsigned short* Qs = (unsigned short*)(ws + 786432);
  unsigned short* Kb = (unsigned short*)(ws + 786432 + 8388608);
  unsigned short* Vt = (unsigned short*)(ws + 786432 + 2 * 8388608);
  unsigned short* op = (unsigned short*)(ws + 786432 + 3 * 8388608);
  float2* ml        = (float2*)(ws + 786432 + 3 * 8388608 + (size_t)NSPLIT * B_ * T_ * D_ * 2);

  tw_kernel<<<dim3(F_ / 64, D_ / 64, 3), 256, 0, stream>>>(Wq, Wk, Wv, Wt);
  proj_kernel<<<dim3((B_ * T_) / 128, D_ / 128, 3), 256, 0, stream>>>(X, Wt, Qs, Kb, Vt);
  flash_kernel<<<dim3(B_, T_ / 64, NSPLIT), 256, 0, stream>>>(Qs, Kb, Vt, op, ml);
  merge_kernel<<<dim3(B_ * T_ / 4), 256, 0, stream>>>(op, ml, out);
}

// Round 4
// 240.653 us; speedup vs baseline: 1.6634x; 1.6634x over previous
//
#include <hip/hip_runtime.h>
#include <cstdint>
#include <cstddef>

#define B_ 8
#define T_ 2048
#define F_ 512
#define D_ 256
#define NSPLIT 2               // KV split; keys per split-block = 1024
#define KVB 64                 // keys per LDS tile
#define NT ((T_ / NSPLIT) / KVB)   // 16 iterations

typedef float f32x4 __attribute__((ext_vector_type(4)));
typedef __bf16 bf16x8 __attribute__((ext_vector_type(8)));
typedef unsigned short us8 __attribute__((ext_vector_type(8)));
typedef unsigned short us4 __attribute__((ext_vector_type(4)));

static __device__ __forceinline__ unsigned short f2bf(float f) {
  union { float f; unsigned int u; } v; v.f = f;
  unsigned int u = v.u;
  u += 0x7fffu + ((u >> 16) & 1u);   // RNE
  return (unsigned short)(u >> 16);
}

static __device__ __forceinline__ float bf2f(unsigned short s) {
  union { float f; unsigned int u; } v; v.u = ((unsigned int)s) << 16;
  return v.f;
}

static __device__ __forceinline__ bf16x8 ldb8(const unsigned short* p) {
  return *reinterpret_cast<const bf16x8*>(p);
}

static __device__ __forceinline__ f32x4 mfma_bf16(bf16x8 a, bf16x8 b, f32x4 c) {
  return __builtin_amdgcn_mfma_f32_16x16x32_bf16(a, b, c, 0, 0, 0);
}

// async global -> LDS, 16 B per lane (dest must be linear: base + lane*16)
static __device__ __forceinline__ void gload_lds16(const unsigned short* g,
                                                   unsigned short* l) {
  __builtin_amdgcn_global_load_lds(
      (const __attribute__((address_space(1))) void*)g,
      (__attribute__((address_space(3))) void*)l, 16, 0, 0);
}

// ---------------------------------------------------------------------------
// Kernel 1: transpose + convert the three W matrices: [F,D] f32 -> [D,F] bf16
// ---------------------------------------------------------------------------
__global__ __launch_bounds__(256) void tw_kernel(const float* __restrict__ Wq,
                                                 const float* __restrict__ Wk,
                                                 const float* __restrict__ Wv,
                                                 unsigned short* __restrict__ Wt) {
  __shared__ unsigned short tile[64][72];
  const float* W = (blockIdx.z == 0) ? Wq : (blockIdx.z == 1) ? Wk : Wv;
  unsigned short* out = Wt + (size_t)blockIdx.z * (D_ * F_);
  int k0 = blockIdx.x * 64, n0 = blockIdx.y * 64;
  int t = threadIdx.x;
#pragma unroll
  for (int i = 0; i < 4; i++) {
    int c = t + 256 * i;
    int r = c >> 4, c4 = (c & 15) * 4;
    float4 v = *reinterpret_cast<const float4*>(&W[(size_t)(k0 + r) * D_ + n0 + c4]);
    us4 p; p[0] = f2bf(v.x); p[1] = f2bf(v.y); p[2] = f2bf(v.z); p[3] = f2bf(v.w);
    *reinterpret_cast<us4*>(&tile[r][c4]) = p;
  }
  __syncthreads();
#pragma unroll
  for (int i = 0; i < 4; i++) {
    int c = t + 256 * i;
    int r = c >> 4, c4 = (c & 15) * 4;
    us4 p;
    p[0] = tile[c4 + 0][r];
    p[1] = tile[c4 + 1][r];
    p[2] = tile[c4 + 2][r];
    p[3] = tile[c4 + 3][r];
    *reinterpret_cast<us4*>(&out[(size_t)(n0 + r) * F_ + k0 + c4]) = p;
  }
}

// ---------------------------------------------------------------------------
// Kernel 2: projection GEMM.  out = X[16384,512] * W  (per z: Q/16, K, V^T)
// ---------------------------------------------------------------------------
__global__ __launch_bounds__(256) void proj_kernel(const float* __restrict__ X,
                                                   const unsigned short* __restrict__ Wt,
                                                   unsigned short* __restrict__ Qs,
                                                   unsigned short* __restrict__ Kb,
                                                   unsigned short* __restrict__ Vt) {
  __shared__ unsigned short Al[128][68];
  __shared__ unsigned short Bl[128][68];
  const int brow = blockIdx.x * 128;
  const int bcol = blockIdx.y * 128;
  const int z = blockIdx.z;
  const unsigned short* W = Wt + (size_t)z * (D_ * F_);
  const int tid = threadIdx.x;
  const int wave = tid >> 6, lane = tid & 63;
  const int wr = wave >> 1, wc = wave & 1;
  const int lg = lane >> 4, lr = lane & 15;

  f32x4 acc[4][4] = {};

  for (int k0 = 0; k0 < F_; k0 += 64) {
#pragma unroll
    for (int i = 0; i < 4; i++) {
      int c = tid + 256 * i;
      int r = c >> 3, off = (c & 7) * 8;
      float4 v0 = *reinterpret_cast<const float4*>(&X[(size_t)(brow + r) * F_ + k0 + off]);
      float4 v1 = *reinterpret_cast<const float4*>(&X[(size_t)(brow + r) * F_ + k0 + off + 4]);
      us8 p;
      p[0] = f2bf(v0.x); p[1] = f2bf(v0.y); p[2] = f2bf(v0.z); p[3] = f2bf(v0.w);
      p[4] = f2bf(v1.x); p[5] = f2bf(v1.y); p[6] = f2bf(v1.z); p[7] = f2bf(v1.w);
      *reinterpret_cast<us8*>(&Al[r][off]) = p;
      *reinterpret_cast<us8*>(&Bl[r][off]) =
          *reinterpret_cast<const us8*>(&W[(size_t)(bcol + r) * F_ + k0 + off]);
    }
    __syncthreads();
#pragma unroll
    for (int kk = 0; kk < 2; kk++) {
      bf16x8 af[4], bfr[4];
#pragma unroll
      for (int mi = 0; mi < 4; mi++) af[mi] = ldb8(&Al[wr * 64 + mi * 16 + lr][kk * 32 + lg * 8]);
#pragma unroll
      for (int ni = 0; ni < 4; ni++) bfr[ni] = ldb8(&Bl[wc * 64 + ni * 16 + lr][kk * 32 + lg * 8]);
#pragma unroll
      for (int mi = 0; mi < 4; mi++)
#pragma unroll
        for (int ni = 0; ni < 4; ni++)
          acc[mi][ni] = mfma_bf16(af[mi], bfr[ni], acc[mi][ni]);
    }
    __syncthreads();
  }

#pragma unroll
  for (int mi = 0; mi < 4; mi++) {
#pragma unroll
    for (int ni = 0; ni < 4; ni++) {
      int row0 = brow + wr * 64 + mi * 16 + lg * 4;
      int col = bcol + wc * 64 + ni * 16 + lr;
      if (z == 0) {
#pragma unroll
        for (int j = 0; j < 4; j++)
          Qs[(size_t)(row0 + j) * D_ + col] = f2bf(acc[mi][ni][j] * 0.0625f);
      } else if (z == 1) {
#pragma unroll
        for (int j = 0; j < 4; j++)
          Kb[(size_t)(row0 + j) * D_ + col] = f2bf(acc[mi][ni][j]);
      } else {
        int b = row0 >> 11, t0 = row0 & (T_ - 1);
        us4 p;
#pragma unroll
        for (int j = 0; j < 4; j++) p[j] = f2bf(acc[mi][ni][j]);
        *reinterpret_cast<us4*>(&Vt[(size_t)b * D_ * T_ + (size_t)col * T_ + t0]) = p;
      }
    }
  }
}

// ---------------------------------------------------------------------------
// Kernel 3: flash attention. grid (B, T/64, NSPLIT), block 256 (4 waves).
// K tile double-buffered in LDS via global_load_lds with XOR-swizzled source
// (linear LDS dest, swizzled ds_read). V direct from global (L1 reuse x4).
// LDS = 64KB K + 8.7KB Pl -> 2 blocks/CU.
// ---------------------------------------------------------------------------
__global__ __launch_bounds__(256, 2) void flash_kernel(const unsigned short* __restrict__ Qs,
                                                       const unsigned short* __restrict__ Kb,
                                                       const unsigned short* __restrict__ Vt,
                                                       unsigned short* __restrict__ op,
                                                       float2* __restrict__ ml) {
  __shared__ unsigned short Kl[2][KVB * 256];   // 2 x 32KB, row-swizzled content
  __shared__ unsigned short Pl[4][16][68];

  const int b = blockIdx.x, qt = blockIdx.y, h = blockIdx.z;  // XCD = linear%8 = b
  const int tid = threadIdx.x;
  const int wave = tid >> 6, lane = tid & 63;
  const int lg = lane >> 4, lr = lane & 15;
  const int swz = (lr & 7) << 4;   // byte XOR for this lane's K rows

  const int qrow = qt * 64 + wave * 16 + lr;
  const unsigned short* qptr = Qs + ((size_t)b * T_ + qrow) * D_;
  bf16x8 qf[8];
#pragma unroll
  for (int ks = 0; ks < 8; ks++) qf[ks] = ldb8(qptr + ks * 32 + lg * 8);

  f32x4 o[16] = {};
  float m[4] = {-__builtin_inff(), -__builtin_inff(), -__builtin_inff(), -__builtin_inff()};
  float lsum[4] = {0.f, 0.f, 0.f, 0.f};

  const int keyoff = h * (T_ / NSPLIT);
  const unsigned short* kbase = Kb + (size_t)b * T_ * D_ + (size_t)keyoff * D_;
  const unsigned short* vbase = Vt + (size_t)b * D_ * T_;

  // stage K tile kt into buffer buf: LDS linear, global source pre-swizzled
  auto stage = [&](int buf, int kt) {
    const unsigned short* src = kbase + (size_t)kt * KVB * D_;
#pragma unroll
    for (int i = 0; i < 8; i++) {
      int L = (tid + 256 * i) * 16;        // LDS byte offset, 0..32767
      int r = L >> 9;                      // tile-local key row
      int c = L & 511;                     // byte col
      int csw = c ^ ((r & 7) << 4);
      gload_lds16(src + r * 256 + (csw >> 1), &Kl[buf][L >> 1]);
    }
  };

  stage(0, 0);
  __syncthreads();

  for (int kt = 0; kt < NT; kt++) {
    const int cur = kt & 1;
    if (kt + 1 < NT) stage(cur ^ 1, kt + 1);   // async prefetch next tile
    const int key0 = keyoff + kt * KVB;

    // ---- S = Q * K^T : K B-fragments from swizzled LDS ----
    f32x4 s[4] = {};
#pragma unroll
    for (int ks = 0; ks < 8; ks++) {
#pragma unroll
      for (int nf = 0; nf < 4; nf++) {
        bf16x8 kb = ldb8(&Kl[cur][(nf * 16 + lr) * 256 + (((ks * 64 + lg * 16) ^ swz) >> 1)]);
        s[nf] = mfma_bf16(qf[ks], kb, s[nf]);
      }
    }

    // ---- online softmax (row q = 4*lg+j, key = 16*nf+lr) ----
    float corr[4];
#pragma unroll
    for (int j = 0; j < 4; j++) {
      float t0 = fmaxf(fmaxf(s[0][j], s[1][j]), fmaxf(s[2][j], s[3][j]));
      t0 = fmaxf(t0, __shfl_xor(t0, 1));
      t0 = fmaxf(t0, __shfl_xor(t0, 2));
      t0 = fmaxf(t0, __shfl_xor(t0, 4));
      t0 = fmaxf(t0, __shfl_xor(t0, 8));
      float mn = fmaxf(m[j], t0);
      corr[j] = __expf(m[j] - mn);
      m[j] = mn;
    }
    float rs[4] = {0.f, 0.f, 0.f, 0.f};
#pragma unroll
    for (int nf = 0; nf < 4; nf++) {
#pragma unroll
      for (int j = 0; j < 4; j++) {
        float p = __expf(s[nf][j] - m[j]);
        rs[j] += p;
        Pl[wave][lg * 4 + j][nf * 16 + lr] = f2bf(p);
      }
    }
#pragma unroll
    for (int j = 0; j < 4; j++) {
      float t0 = rs[j];
      t0 += __shfl_xor(t0, 1);
      t0 += __shfl_xor(t0, 2);
      t0 += __shfl_xor(t0, 4);
      t0 += __shfl_xor(t0, 8);
      lsum[j] = lsum[j] * corr[j] + t0;
    }
#pragma unroll
    for (int nf = 0; nf < 16; nf++) {
#pragma unroll
      for (int j = 0; j < 4; j++) o[nf][j] *= corr[j];
    }

    // ---- O += P * V : V^T B-fragments from global (L1-resident) ----
#pragma unroll
    for (int ks = 0; ks < 2; ks++) {
      bf16x8 pa = ldb8(&Pl[wave][lr][ks * 32 + lg * 8]);
#pragma unroll
      for (int nf = 0; nf < 16; nf++) {
        bf16x8 vb = ldb8(&vbase[(size_t)(nf * 16 + lr) * T_ + key0 + ks * 32 + lg * 8]);
        o[nf] = mfma_bf16(pa, vb, o[nf]);
      }
    }

    __syncthreads();   // drains stage loads; next iter flips buffers
  }

  // ---- write partials (unnormalized o in bf16, m/l in f32) ----
  const size_t rowbase = (size_t)h * (B_ * T_) + (size_t)b * T_;
#pragma unroll
  for (int nf = 0; nf < 16; nf++) {
#pragma unroll
    for (int j = 0; j < 4; j++) {
      int q = qt * 64 + wave * 16 + lg * 4 + j;
      op[(rowbase + q) * D_ + nf * 16 + lr] = f2bf(o[nf][j]);
    }
  }
  if (lr == 0) {
#pragma unroll
    for (int j = 0; j < 4; j++) {
      int q = qt * 64 + wave * 16 + lg * 4 + j;
      ml[rowbase + q] = make_float2(m[j], lsum[j]);
    }
  }
}

// ---------------------------------------------------------------------------
// Kernel 4: merge NSPLIT partials.  grid (B*T/4), block 256: 4 rows/block.
// ---------------------------------------------------------------------------
__global__ __launch_bounds__(256) void merge_kernel(const unsigned short* __restrict__ op,
                                                    const float2* __restrict__ ml,
                                                    float* __restrict__ out) {
  const int tid = threadIdx.x;
  const int row = blockIdx.x * 4 + (tid >> 6);
  const int d0 = (tid & 63) * 4;

  float mh[NSPLIT], lh[NSPLIT];
  float M = -__builtin_inff();
#pragma unroll
  for (int hh = 0; hh < NSPLIT; hh++) {
    float2 v = ml[(size_t)hh * (B_ * T_) + row];
    mh[hh] = v.x; lh[hh] = v.y;
    M = fmaxf(M, v.x);
  }
  float e[NSPLIT], den = 0.f;
#pragma unroll
  for (int hh = 0; hh < NSPLIT; hh++) {
    e[hh] = __expf(mh[hh] - M);
    den += e[hh] * lh[hh];
  }
  const float inv = 1.0f / den;

  float acc[4] = {0.f, 0.f, 0.f, 0.f};
#pragma unroll
  for (int hh = 0; hh < NSPLIT; hh++) {
    us4 p = *reinterpret_cast<const us4*>(
        &op[((size_t)hh * (B_ * T_) + row) * D_ + d0]);
#pragma unroll
    for (int j = 0; j < 4; j++) acc[j] += e[hh] * bf2f(p[j]);
  }
  float4 r;
  r.x = acc[0] * inv; r.y = acc[1] * inv; r.z = acc[2] * inv; r.w = acc[3] * inv;
  *reinterpret_cast<float4*>(&out[(size_t)row * D_ + d0]) = r;
}

// ---------------------------------------------------------------------------
extern "C" void kernel_launch(void* const* d_in, const int* in_sizes, int n_in,
                              void* d_out, int out_size, void* d_ws, size_t ws_size,
                              hipStream_t stream) {
  const float* X  = (const float*)d_in[0];
  const float* Wq = (const float*)d_in[1];
  const float* Wk = (const float*)d_in[2];
  const float* Wv = (const float*)d_in[3];
  float* out = (float*)d_out;

  char* ws = (char*)d_ws;
  // Wt 0.75MB | Qs 8MB | Kb 8MB | Vt 8MB | op 16MB | ml 0.25MB
  unsigned short* Wt = (unsigned short*)ws;
  unsigned short* Qs = (unsigned short*)(ws + 786432);
  unsigned short* Kb = (unsigned short*)(ws + 786432 + 8388608);
  unsigned short* Vt = (unsigned short*)(ws + 786432 + 2 * 8388608);
  unsigned short* op = (unsigned short*)(ws + 786432 + 3 * 8388608);
  float2* ml        = (float2*)(ws + 786432 + 3 * 8388608 + (size_t)NSPLIT * B_ * T_ * D_ * 2);

  tw_kernel<<<dim3(F_ / 64, D_ / 64, 3), 256, 0, stream>>>(Wq, Wk, Wv, Wt);
  proj_kernel<<<dim3((B_ * T_) / 128, D_ / 128, 3), 256, 0, stream>>>(X, Wt, Qs, Kb, Vt);
  flash_kernel<<<dim3(B_, T_ / 64, NSPLIT), 256, 0, stream>>>(Qs, Kb, Vt, op, ml);
  merge_kernel<<<dim3(B_ * T_ / 4), 256, 0, stream>>>(op, ml, out);
}

// Round 5
// 212.617 us; speedup vs baseline: 1.8827x; 1.1319x over previous
//
#include <hip/hip_runtime.h>
#include <cstdint>
#include <cstddef>

#define B_ 8
#define T_ 2048
#define F_ 512
#define D_ 256
#define NSPLIT 2               // KV split; keys per split-block = 1024
#define KVB 64                 // keys per LDS tile
#define NT ((T_ / NSPLIT) / KVB)   // 16 iterations

typedef float f32x4 __attribute__((ext_vector_type(4)));
typedef __bf16 bf16x8 __attribute__((ext_vector_type(8)));
typedef unsigned short us8 __attribute__((ext_vector_type(8)));
typedef unsigned short us4 __attribute__((ext_vector_type(4)));

static __device__ __forceinline__ unsigned short f2bf(float f) {
  union { float f; unsigned int u; } v; v.f = f;
  unsigned int u = v.u;
  u += 0x7fffu + ((u >> 16) & 1u);   // RNE
  return (unsigned short)(u >> 16);
}

static __device__ __forceinline__ float bf2f(unsigned short s) {
  union { float f; unsigned int u; } v; v.u = ((unsigned int)s) << 16;
  return v.f;
}

static __device__ __forceinline__ bf16x8 ldb8(const unsigned short* p) {
  return *reinterpret_cast<const bf16x8*>(p);
}

static __device__ __forceinline__ f32x4 mfma_bf16(bf16x8 a, bf16x8 b, f32x4 c) {
  return __builtin_amdgcn_mfma_f32_16x16x32_bf16(a, b, c, 0, 0, 0);
}

// async global -> LDS, 16 B per lane (dest must be linear: base + lane*16)
static __device__ __forceinline__ void gload_lds16(const unsigned short* g,
                                                   unsigned short* l) {
  __builtin_amdgcn_global_load_lds(
      (const __attribute__((address_space(1))) void*)g,
      (__attribute__((address_space(3))) void*)l, 16, 0, 0);
}

// ---------------------------------------------------------------------------
// Kernel 1: transpose + convert the three W matrices: [F,D] f32 -> [D,F] bf16
// ---------------------------------------------------------------------------
__global__ __launch_bounds__(256) void tw_kernel(const float* __restrict__ Wq,
                                                 const float* __restrict__ Wk,
                                                 const float* __restrict__ Wv,
                                                 unsigned short* __restrict__ Wt) {
  __shared__ unsigned short tile[64][72];
  const float* W = (blockIdx.z == 0) ? Wq : (blockIdx.z == 1) ? Wk : Wv;
  unsigned short* out = Wt + (size_t)blockIdx.z * (D_ * F_);
  int k0 = blockIdx.x * 64, n0 = blockIdx.y * 64;
  int t = threadIdx.x;
#pragma unroll
  for (int i = 0; i < 4; i++) {
    int c = t + 256 * i;
    int r = c >> 4, c4 = (c & 15) * 4;
    float4 v = *reinterpret_cast<const float4*>(&W[(size_t)(k0 + r) * D_ + n0 + c4]);
    us4 p; p[0] = f2bf(v.x); p[1] = f2bf(v.y); p[2] = f2bf(v.z); p[3] = f2bf(v.w);
    *reinterpret_cast<us4*>(&tile[r][c4]) = p;
  }
  __syncthreads();
#pragma unroll
  for (int i = 0; i < 4; i++) {
    int c = t + 256 * i;
    int r = c >> 4, c4 = (c & 15) * 4;
    us4 p;
    p[0] = tile[c4 + 0][r];
    p[1] = tile[c4 + 1][r];
    p[2] = tile[c4 + 2][r];
    p[3] = tile[c4 + 3][r];
    *reinterpret_cast<us4*>(&out[(size_t)(n0 + r) * F_ + k0 + c4]) = p;
  }
}

// ---------------------------------------------------------------------------
// Kernel 2: projection GEMM.  out = X[16384,512] * W  (per z: Q/16, K, V^T)
// ---------------------------------------------------------------------------
__global__ __launch_bounds__(256) void proj_kernel(const float* __restrict__ X,
                                                   const unsigned short* __restrict__ Wt,
                                                   unsigned short* __restrict__ Qs,
                                                   unsigned short* __restrict__ Kb,
                                                   unsigned short* __restrict__ Vt) {
  __shared__ unsigned short Al[128][68];
  __shared__ unsigned short Bl[128][68];
  const int brow = blockIdx.x * 128;
  const int bcol = blockIdx.y * 128;
  const int z = blockIdx.z;
  const unsigned short* W = Wt + (size_t)z * (D_ * F_);
  const int tid = threadIdx.x;
  const int wave = tid >> 6, lane = tid & 63;
  const int wr = wave >> 1, wc = wave & 1;
  const int lg = lane >> 4, lr = lane & 15;

  f32x4 acc[4][4] = {};

  for (int k0 = 0; k0 < F_; k0 += 64) {
#pragma unroll
    for (int i = 0; i < 4; i++) {
      int c = tid + 256 * i;
      int r = c >> 3, off = (c & 7) * 8;
      float4 v0 = *reinterpret_cast<const float4*>(&X[(size_t)(brow + r) * F_ + k0 + off]);
      float4 v1 = *reinterpret_cast<const float4*>(&X[(size_t)(brow + r) * F_ + k0 + off + 4]);
      us8 p;
      p[0] = f2bf(v0.x); p[1] = f2bf(v0.y); p[2] = f2bf(v0.z); p[3] = f2bf(v0.w);
      p[4] = f2bf(v1.x); p[5] = f2bf(v1.y); p[6] = f2bf(v1.z); p[7] = f2bf(v1.w);
      *reinterpret_cast<us8*>(&Al[r][off]) = p;
      *reinterpret_cast<us8*>(&Bl[r][off]) =
          *reinterpret_cast<const us8*>(&W[(size_t)(bcol + r) * F_ + k0 + off]);
    }
    __syncthreads();
#pragma unroll
    for (int kk = 0; kk < 2; kk++) {
      bf16x8 af[4], bfr[4];
#pragma unroll
      for (int mi = 0; mi < 4; mi++) af[mi] = ldb8(&Al[wr * 64 + mi * 16 + lr][kk * 32 + lg * 8]);
#pragma unroll
      for (int ni = 0; ni < 4; ni++) bfr[ni] = ldb8(&Bl[wc * 64 + ni * 16 + lr][kk * 32 + lg * 8]);
#pragma unroll
      for (int mi = 0; mi < 4; mi++)
#pragma unroll
        for (int ni = 0; ni < 4; ni++)
          acc[mi][ni] = mfma_bf16(af[mi], bfr[ni], acc[mi][ni]);
    }
    __syncthreads();
  }

#pragma unroll
  for (int mi = 0; mi < 4; mi++) {
#pragma unroll
    for (int ni = 0; ni < 4; ni++) {
      int row0 = brow + wr * 64 + mi * 16 + lg * 4;
      int col = bcol + wc * 64 + ni * 16 + lr;
      if (z == 0) {
#pragma unroll
        for (int j = 0; j < 4; j++)
          Qs[(size_t)(row0 + j) * D_ + col] = f2bf(acc[mi][ni][j] * 0.0625f);
      } else if (z == 1) {
#pragma unroll
        for (int j = 0; j < 4; j++)
          Kb[(size_t)(row0 + j) * D_ + col] = f2bf(acc[mi][ni][j]);
      } else {
        int b = row0 >> 11, t0 = row0 & (T_ - 1);
        us4 p;
#pragma unroll
        for (int j = 0; j < 4; j++) p[j] = f2bf(acc[mi][ni][j]);
        *reinterpret_cast<us4*>(&Vt[(size_t)b * D_ * T_ + (size_t)col * T_ + t0]) = p;
      }
    }
  }
}

// ---------------------------------------------------------------------------
// Kernel 3: flash attention. grid (B, T/64, NSPLIT), block 256 (4 waves).
// Swapped QK^T (S^T = K*Q^T) -> softmax lane-local per q; defer-max rescale;
// V ks=0 prefetched to registers; K double-buffered swizzled LDS.
// ---------------------------------------------------------------------------
__global__ __launch_bounds__(256, 2) void flash_kernel(const unsigned short* __restrict__ Qs,
                                                       const unsigned short* __restrict__ Kb,
                                                       const unsigned short* __restrict__ Vt,
                                                       unsigned short* __restrict__ op,
                                                       float2* __restrict__ ml) {
  __shared__ unsigned short Kl[2][KVB * 256];   // 2 x 32KB, row-swizzled content
  __shared__ unsigned short Pl[4][16][68];      // P in PV-A layout: [q][key]

  const int b = blockIdx.x, qt = blockIdx.y, h = blockIdx.z;  // XCD = linear%8 = b
  const int tid = threadIdx.x;
  const int wave = tid >> 6, lane = tid & 63;
  const int lg = lane >> 4, lr = lane & 15;
  const int swz = (lr & 7) << 4;   // byte XOR for this lane's K rows

  const int qrow = qt * 64 + wave * 16 + lr;
  const unsigned short* qptr = Qs + ((size_t)b * T_ + qrow) * D_;
  bf16x8 qf[8];
#pragma unroll
  for (int ks = 0; ks < 8; ks++) qf[ks] = ldb8(qptr + ks * 32 + lg * 8);

  f32x4 o[16] = {};
  float m = -__builtin_inff();   // running max for q = lr (replicated over lg)
  float lsum = 0.f;              // running denom for q = lr

  const int keyoff = h * (T_ / NSPLIT);
  const unsigned short* kbase = Kb + (size_t)b * T_ * D_ + (size_t)keyoff * D_;
  const unsigned short* vbase = Vt + (size_t)b * D_ * T_;

  auto stage = [&](int buf, int kt) {
    const unsigned short* src = kbase + (size_t)kt * KVB * D_;
#pragma unroll
    for (int i = 0; i < 8; i++) {
      int L = (tid + 256 * i) * 16;        // LDS byte offset, 0..32767
      int r = L >> 9;                      // tile-local key row
      int c = L & 511;                     // byte col
      int csw = c ^ ((r & 7) << 4);
      gload_lds16(src + r * 256 + (csw >> 1), &Kl[buf][L >> 1]);
    }
  };

  stage(0, 0);
  __syncthreads();

  for (int kt = 0; kt < NT; kt++) {
    const int cur = kt & 1;
    if (kt + 1 < NT) stage(cur ^ 1, kt + 1);   // async prefetch next tile
    const int key0 = keyoff + kt * KVB;

    // ---- S^T = K * Q^T : lane holds 16 scores, all for q = lr ----
    // s[nf][j] = score(q=lr, key = nf*16 + 4*lg + j)
    f32x4 s[4] = {};
    __builtin_amdgcn_s_setprio(1);
#pragma unroll
    for (int ks = 0; ks < 8; ks++) {
#pragma unroll
      for (int nf = 0; nf < 4; nf++) {
        bf16x8 kb = ldb8(&Kl[cur][(nf * 16 + lr) * 256 + (((ks * 64 + lg * 16) ^ swz) >> 1)]);
        s[nf] = mfma_bf16(kb, qf[ks], s[nf]);
      }
    }
    __builtin_amdgcn_s_setprio(0);

    // ---- prefetch V ks=0 fragments (latency hidden under softmax) ----
    bf16x8 v0[16];
#pragma unroll
    for (int nf = 0; nf < 16; nf++)
      v0[nf] = ldb8(&vbase[(size_t)(nf * 16 + lr) * T_ + key0 + lg * 8]);

    // ---- lane-local softmax for q = lr ----
    float pm;
    {
      float a0 = fmaxf(fmaxf(s[0][0], s[0][1]), fmaxf(s[0][2], s[0][3]));
      float a1 = fmaxf(fmaxf(s[1][0], s[1][1]), fmaxf(s[1][2], s[1][3]));
      float a2 = fmaxf(fmaxf(s[2][0], s[2][1]), fmaxf(s[2][2], s[2][3]));
      float a3 = fmaxf(fmaxf(s[3][0], s[3][1]), fmaxf(s[3][2], s[3][3]));
      pm = fmaxf(fmaxf(a0, a1), fmaxf(a2, a3));
      pm = fmaxf(pm, __shfl_xor(pm, 16));
      pm = fmaxf(pm, __shfl_xor(pm, 32));
    }
    if (!__all(pm - m <= 8.0f)) {            // defer-max (T13, THR=8)
      float mn = fmaxf(m, pm);
      float corr = __expf(m - mn);
      m = mn;
      lsum *= corr;
      float c4[4];
#pragma unroll
      for (int j = 0; j < 4; j++) c4[j] = __shfl(corr, lg * 4 + j);  // corr for q=4lg+j
#pragma unroll
      for (int nf = 0; nf < 16; nf++)
#pragma unroll
        for (int j = 0; j < 4; j++) o[nf][j] *= c4[j];
    }
    float rs = 0.f;
#pragma unroll
    for (int nf = 0; nf < 4; nf++) {
      us4 pk;
#pragma unroll
      for (int j = 0; j < 4; j++) {
        float p = __expf(s[nf][j] - m);
        rs += p;
        pk[j] = f2bf(p);
      }
      *reinterpret_cast<us4*>(&Pl[wave][lr][nf * 16 + lg * 4]) = pk;
    }
    rs += __shfl_xor(rs, 16);
    rs += __shfl_xor(rs, 32);
    lsum += rs;

    // ---- O += P * V ----
    __builtin_amdgcn_s_setprio(1);
    {
      bf16x8 pa = ldb8(&Pl[wave][lr][lg * 8]);
#pragma unroll
      for (int nf = 0; nf < 16; nf++) o[nf] = mfma_bf16(pa, v0[nf], o[nf]);
    }
    {
      bf16x8 pa = ldb8(&Pl[wave][lr][32 + lg * 8]);
#pragma unroll
      for (int nf = 0; nf < 16; nf++) {
        bf16x8 vb = ldb8(&vbase[(size_t)(nf * 16 + lr) * T_ + key0 + 32 + lg * 8]);
        o[nf] = mfma_bf16(pa, vb, o[nf]);
      }
    }
    __builtin_amdgcn_s_setprio(0);

    __syncthreads();   // drains stage loads; next iter flips buffers
  }

  // ---- write partials (unnormalized o in bf16; m/l in f32 at q = lr) ----
  const size_t rowbase = (size_t)h * (B_ * T_) + (size_t)b * T_;
#pragma unroll
  for (int nf = 0; nf < 16; nf++) {
#pragma unroll
    for (int j = 0; j < 4; j++) {
      int q = qt * 64 + wave * 16 + lg * 4 + j;
      op[(rowbase + q) * D_ + nf * 16 + lr] = f2bf(o[nf][j]);
    }
  }
  if (lg == 0) {
    int q = qt * 64 + wave * 16 + lr;
    ml[rowbase + q] = make_float2(m, lsum);
  }
}

// ---------------------------------------------------------------------------
// Kernel 4: merge NSPLIT partials.  grid (B*T/4), block 256: 4 rows/block.
// ---------------------------------------------------------------------------
__global__ __launch_bounds__(256) void merge_kernel(const unsigned short* __restrict__ op,
                                                    const float2* __restrict__ ml,
                                                    float* __restrict__ out) {
  const int tid = threadIdx.x;
  const int row = blockIdx.x * 4 + (tid >> 6);
  const int d0 = (tid & 63) * 4;

  float mh[NSPLIT], lh[NSPLIT];
  float M = -__builtin_inff();
#pragma unroll
  for (int hh = 0; hh < NSPLIT; hh++) {
    float2 v = ml[(size_t)hh * (B_ * T_) + row];
    mh[hh] = v.x; lh[hh] = v.y;
    M = fmaxf(M, v.x);
  }
  float e[NSPLIT], den = 0.f;
#pragma unroll
  for (int hh = 0; hh < NSPLIT; hh++) {
    e[hh] = __expf(mh[hh] - M);
    den += e[hh] * lh[hh];
  }
  const float inv = 1.0f / den;

  float acc[4] = {0.f, 0.f, 0.f, 0.f};
#pragma unroll
  for (int hh = 0; hh < NSPLIT; hh++) {
    us4 p = *reinterpret_cast<const us4*>(
        &op[((size_t)hh * (B_ * T_) + row) * D_ + d0]);
#pragma unroll
    for (int j = 0; j < 4; j++) acc[j] += e[hh] * bf2f(p[j]);
  }
  float4 r;
  r.x = acc[0] * inv; r.y = acc[1] * inv; r.z = acc[2] * inv; r.w = acc[3] * inv;
  *reinterpret_cast<float4*>(&out[(size_t)row * D_ + d0]) = r;
}

// ---------------------------------------------------------------------------
extern "C" void kernel_launch(void* const* d_in, const int* in_sizes, int n_in,
                              void* d_out, int out_size, void* d_ws, size_t ws_size,
                              hipStream_t stream) {
  const float* X  = (const float*)d_in[0];
  const float* Wq = (const float*)d_in[1];
  const float* Wk = (const float*)d_in[2];
  const float* Wv = (const float*)d_in[3];
  float* out = (float*)d_out;

  char* ws = (char*)d_ws;
  // Wt 0.75MB | Qs 8MB | Kb 8MB | Vt 8MB | op 16MB | ml 0.25MB
  unsigned short* Wt = (unsigned short*)ws;
  unsigned short* Qs = (unsigned short*)(ws + 786432);
  unsigned short* Kb = (unsigned short*)(ws + 786432 + 8388608);
  unsigned short* Vt = (unsigned short*)(ws + 786432 + 2 * 8388608);
  unsigned short* op = (unsigned short*)(ws + 786432 + 3 * 8388608);
  float2* ml        = (float2*)(ws + 786432 + 3 * 8388608 + (size_t)NSPLIT * B_ * T_ * D_ * 2);

  tw_kernel<<<dim3(F_ / 64, D_ / 64, 3), 256, 0, stream>>>(Wq, Wk, Wv, Wt);
  proj_kernel<<<dim3((B_ * T_) / 128, D_ / 128, 3), 256, 0, stream>>>(X, Wt, Qs, Kb, Vt);
  flash_kernel<<<dim3(B_, T_ / 64, NSPLIT), 256, 0, stream>>>(Qs, Kb, Vt, op, ml);
  merge_kernel<<<dim3(B_ * T_ / 4), 256, 0, stream>>>(op, ml, out);
}